// Round 1
// baseline (190.426 us; speedup 1.0000x reference)
//
#include <hip/hip_runtime.h>
#include <math.h>

#define D 128
#define C 64
#define P1_THREADS 256
#define P1_UNROLL 8

// Phase 1: per-block segment max. Two LDS buffers (one per row-parity group of
// 128 threads); each thread owns a single dim column -> race-free max updates.
__global__ __launch_bounds__(P1_THREADS) void p1_segmax(
    const int* __restrict__ assign, const float* __restrict__ qe,
    float* __restrict__ part, int Q, int ntiles) {
  __shared__ float buf[2][C * D];  // 64 KB
  int tid = threadIdx.x;
  float* flat = &buf[0][0];
  for (int i = tid; i < 2 * C * D; i += P1_THREADS) flat[i] = -INFINITY;
  __syncthreads();

  int p = tid >> 7;   // row-parity group 0/1
  int t = tid & 127;  // dim column
  float* mybuf = buf[p];

  for (int tile = blockIdx.x; tile < ntiles; tile += gridDim.x) {
    int base = tile * (2 * P1_UNROLL) + p * P1_UNROLL;
    if (base + P1_UNROLL <= Q) {
      float v[P1_UNROLL];
      int a[P1_UNROLL];
#pragma unroll
      for (int i = 0; i < P1_UNROLL; ++i) {
        v[i] = qe[(base + i) * D + t];
        a[i] = assign[base + i];
      }
#pragma unroll
      for (int i = 0; i < P1_UNROLL; ++i) {
        int idx = a[i] * D + t;
        mybuf[idx] = fmaxf(mybuf[idx], v[i]);
      }
    } else {
      for (int i = 0; i < P1_UNROLL; ++i) {
        int q = base + i;
        if (q < Q) {
          float v = qe[q * D + t];
          int idx = assign[q] * D + t;
          mybuf[idx] = fmaxf(mybuf[idx], v);
        }
      }
    }
  }
  __syncthreads();

  float* outp = part + (size_t)blockIdx.x * (C * D);
  for (int i = tid; i < C * D; i += P1_THREADS)
    outp[i] = fmaxf(buf[0][i], buf[1][i]);
}

// Phase 2: reduce nb partial buffers -> core_embs, apply padding for empty cores.
// Block = 16 outputs x 16 readers.
__global__ __launch_bounds__(256) void p2_merge(
    const float* __restrict__ part, const float* __restrict__ padding,
    float* __restrict__ core_embs, int nb) {
  __shared__ float red[256];
  int tid = threadIdx.x;
  int o_local = tid & 15;
  int r = tid >> 4;
  int o = blockIdx.x * 16 + o_local;
  float m = -INFINITY;
  for (int br = r; br < nb; br += 16)
    m = fmaxf(m, part[(size_t)br * (C * D) + o]);
  red[tid] = m;
  __syncthreads();
  for (int s = 8; s >= 1; s >>= 1) {
    if (r < s)
      red[r * 16 + o_local] = fmaxf(red[r * 16 + o_local], red[(r + s) * 16 + o_local]);
    __syncthreads();
  }
  if (r == 0) {
    float v = red[o_local];
    if (v == -INFINITY) v = padding[o & (D - 1)];  // empty segment
    core_embs[o] = v;
  }
}

// Phase 3a: tmp = core_embs @ W_msg   [C,D] x [D,D]
__global__ __launch_bounds__(D) void p3a_gemm(
    const float* __restrict__ core_embs, const float* __restrict__ Wmsg,
    float* __restrict__ tmp) {
  __shared__ float xrow[D];
  int t = threadIdx.x;
  int j = blockIdx.x;
  xrow[t] = core_embs[j * D + t];
  __syncthreads();
  float acc = 0.f;
#pragma unroll 8
  for (int k = 0; k < D; ++k) acc += xrow[k] * Wmsg[k * D + t];
  tmp[j * D + t] = acc;
}

// Phase 3b: out = relu(core_embs @ W_self + core_con @ tmp + b)
__global__ __launch_bounds__(D) void p3b_out(
    const float* __restrict__ core_embs, const float* __restrict__ con,
    const float* __restrict__ tmp, const float* __restrict__ Wself,
    const float* __restrict__ b, float* __restrict__ out) {
  __shared__ float ce[D];
  __shared__ float cr[C];
  int t = threadIdx.x;
  int c = blockIdx.x;
  ce[t] = core_embs[c * D + t];
  if (t < C) cr[t] = con[c * C + t];
  __syncthreads();
  float acc = b[t];
#pragma unroll 8
  for (int k = 0; k < D; ++k) acc += ce[k] * Wself[k * D + t];
#pragma unroll 8
  for (int j = 0; j < C; ++j) acc += cr[j] * tmp[j * D + t];
  out[c * D + t] = fmaxf(acc, 0.f);
}

extern "C" void kernel_launch(void* const* d_in, const int* in_sizes, int n_in,
                              void* d_out, int out_size, void* d_ws, size_t ws_size,
                              hipStream_t stream) {
  const int* assign   = (const int*)d_in[0];
  const float* qe     = (const float*)d_in[1];
  const float* padding= (const float*)d_in[2];
  const float* con    = (const float*)d_in[3];
  const float* Wself  = (const float*)d_in[4];
  const float* Wmsg   = (const float*)d_in[5];
  const float* b      = (const float*)d_in[6];
  float* out = (float*)d_out;
  int Q = in_sizes[0];

  const size_t slot = (size_t)C * D;  // 8192 floats = 32 KB
  size_t avail_f = ws_size / sizeof(float);
  long nb_max = (long)((avail_f > 2 * slot ? avail_f - 2 * slot : slot) / slot);
  int nb = (int)(nb_max < 512 ? nb_max : 512);
  if (nb < 1) nb = 1;

  float* part      = (float*)d_ws;
  float* core_embs = part + (size_t)nb * slot;
  float* tmp       = core_embs + slot;

  int ntiles = (Q + 2 * P1_UNROLL - 1) / (2 * P1_UNROLL);

  hipLaunchKernelGGL(p1_segmax, dim3(nb), dim3(P1_THREADS), 0, stream,
                     assign, qe, part, Q, ntiles);
  hipLaunchKernelGGL(p2_merge, dim3((C * D) / 16), dim3(256), 0, stream,
                     part, padding, core_embs, nb);
  hipLaunchKernelGGL(p3a_gemm, dim3(C), dim3(D), 0, stream,
                     core_embs, Wmsg, tmp);
  hipLaunchKernelGGL(p3b_out, dim3(C), dim3(D), 0, stream,
                     core_embs, con, tmp, Wself, b, out);
}